// Round 3
// baseline (474.375 us; speedup 1.0000x reference)
//
#include <hip/hip_runtime.h>
#include <hip/hip_bf16.h>

typedef __attribute__((ext_vector_type(8))) short bf16x8;
typedef __attribute__((ext_vector_type(4))) float f32x4;
typedef __attribute__((ext_vector_type(4))) unsigned short u16x4;
typedef __attribute__((ext_vector_type(8))) unsigned short u16x8;

__device__ __forceinline__ unsigned short f2bf(float f) {
  unsigned u = __float_as_uint(f);
  u += 0x7FFF + ((u >> 16) & 1);   // RNE
  return (unsigned short)(u >> 16);
}
__device__ __forceinline__ float bf2f(unsigned short h) {
  return __uint_as_float(((unsigned)h) << 16);
}

__device__ __forceinline__ void gll16(const void* g, void* l) {
  __builtin_amdgcn_global_load_lds(
      (const __attribute__((address_space(1))) void*)g,
      (__attribute__((address_space(3))) void*)l, 16, 0, 0);
}

// ---------------------------------------------------------------------------
// bf16 MFMA GEMM:  C[bz] = A[bz] (MxK, k-inner) * B[bz]^T  (B is [N][K] k-inner)
// Tile BM x BN, BK=32, WM x WN waves (64x? per wave). Ring-4 LDS buffers,
// depth-2 prefetch with counted vmcnt(8), ONE barrier per K-subtile.
//
// LDS layout per operand tile (R rows x 32 k bf16): rows paired into 128B
// lines; 16B chunk (row, s) stored at line=row>>1, phys8=(s+4*(row&1))^(line&7).
// Staged linearly (chunk g -> byte g*16) with inverse-swizzled global source
// (rule #21), read with the same swizzle -> <=2 lanes per slot (free).
//
// MODE 0: bf16 store. MODE 1: per-COLUMN BN (bn=[4][N]) + ReLU, bf16 store.
// MODE 2: fp32 store.  Requires M%BM==0, N%BN==0, K%32==0, K/32 >= 2.
// ---------------------------------------------------------------------------
template <int BM, int BN, int WM, int WN, int MODE>
__global__ __launch_bounds__(WM* WN * 64) void gemm_mfma(
    const unsigned short* __restrict__ A, long abs_,
    const unsigned short* __restrict__ B, long bbs,
    void* __restrict__ Cv, long cbs, int ldC,
    int M, int N, int K,
    const float* __restrict__ bn)
{
  constexpr int T = WM * WN * 64;
  constexpr int MI = BM / WM / 16;    // A frags per wave
  constexpr int NJ = BN / WN / 16;    // B frags per wave
  constexpr int BUFB = (BM + BN) * 64;  // bytes per ring slot
  constexpr int CA = BM * 4 / T;      // A 16B-chunks per thread per subtile
  constexpr int CB = BN * 4 / T;
  __shared__ char smem[4 * BUFB];

  const int tid = threadIdx.x;
  const int w = tid >> 6, lane = tid & 63;
  const int wr = w / WN, wc = w % WN;
  const int llo = lane & 15, lhi = lane >> 4;
  const int bz = blockIdx.z;
  const int m0 = blockIdx.y * BM, n0 = blockIdx.x * BN;
  const unsigned short* Ab = A + (long)bz * abs_;
  const unsigned short* Bb = B + (long)bz * bbs;
  const int NT = K >> 5;

  // staging descriptors (element offsets into A/B, byte offsets into LDS)
  long aoff[CA]; int adst[CA];
#pragma unroll
  for (int i = 0; i < CA; ++i) {
    int g = i * T + tid;
    int line = g >> 3, ph = g & 7;
    int t8 = ph ^ (line & 7);
    int row = line * 2 + (t8 >> 2);
    aoff[i] = (long)(m0 + row) * K + (t8 & 3) * 8;
    adst[i] = g * 16;
  }
  long boff[CB]; int bdst[CB];
#pragma unroll
  for (int i = 0; i < CB; ++i) {
    int g = i * T + tid;
    int line = g >> 3, ph = g & 7;
    int t8 = ph ^ (line & 7);
    int row = line * 2 + (t8 >> 2);
    boff[i] = (long)(n0 + row) * K + (t8 & 3) * 8;
    bdst[i] = g * 16;
  }

  // ds_read byte offsets (swizzled), loop-invariant
  int aro[MI];
#pragma unroll
  for (int i = 0; i < MI; ++i) {
    int row = wr * (BM / WM) + i * 16 + llo;
    int line = row >> 1;
    int ph = (lhi + ((row & 1) << 2)) ^ (line & 7);
    aro[i] = line * 128 + ph * 16;
  }
  int bro[NJ];
#pragma unroll
  for (int j = 0; j < NJ; ++j) {
    int col = wc * (BN / WN) + j * 16 + llo;
    int line = col >> 1;
    int ph = (lhi + ((col & 1) << 2)) ^ (line & 7);
    bro[j] = line * 128 + ph * 16;
  }

  auto stage = [&](int t, int buf) {
    const long ko = (long)t * 32;
    char* ab = smem + buf * BUFB;
    char* bb2 = ab + BM * 64;
#pragma unroll
    for (int i = 0; i < CA; ++i) gll16(Ab + aoff[i] + ko, ab + adst[i]);
#pragma unroll
    for (int i = 0; i < CB; ++i) gll16(Bb + boff[i] + ko, bb2 + bdst[i]);
  };

  f32x4 acc[MI][NJ];
#pragma unroll
  for (int i = 0; i < MI; ++i)
#pragma unroll
    for (int j = 0; j < NJ; ++j) acc[i][j] = (f32x4)0.f;

  stage(0, 0);
  stage(1, 1);

  for (int t = 0; t < NT; ++t) {
    if (t + 2 < NT) {
      stage(t + 2, (t + 2) & 3);
      asm volatile("s_waitcnt vmcnt(8)" ::: "memory");  // subtile t landed
    } else if (t + 1 < NT) {
      asm volatile("s_waitcnt vmcnt(4)" ::: "memory");
    } else {
      asm volatile("s_waitcnt vmcnt(0)" ::: "memory");
    }
    __builtin_amdgcn_s_barrier();

    char* ab = smem + (t & 3) * BUFB;
    char* bb2 = ab + BM * 64;
    bf16x8 af[MI], bfr[NJ];
#pragma unroll
    for (int i = 0; i < MI; ++i) af[i] = *(const bf16x8*)(ab + aro[i]);
#pragma unroll
    for (int j = 0; j < NJ; ++j) bfr[j] = *(const bf16x8*)(bb2 + bro[j]);
    __builtin_amdgcn_s_setprio(1);
#pragma unroll
    for (int i = 0; i < MI; ++i)
#pragma unroll
      for (int j = 0; j < NJ; ++j)
        acc[i][j] = __builtin_amdgcn_mfma_f32_16x16x32_bf16(af[i], bfr[j], acc[i][j], 0, 0, 0);
    __builtin_amdgcn_s_setprio(0);
  }

  // epilogue: C/D frag mapping col = lane&15, row = (lane>>4)*4 + e
  const int gm = m0 + wr * (BM / WM) + lhi * 4;
  const int gn = n0 + wc * (BN / WN) + llo;
  if constexpr (MODE == 2) {
    float* Cb = (float*)Cv + (long)bz * cbs;
#pragma unroll
    for (int i = 0; i < MI; ++i)
#pragma unroll
      for (int j = 0; j < NJ; ++j)
#pragma unroll
        for (int e = 0; e < 4; ++e)
          Cb[(long)(gm + i * 16 + e) * ldC + gn + j * 16] = acc[i][j][e];
  } else {
    unsigned short* Cb = (unsigned short*)Cv + (long)bz * cbs;
#pragma unroll
    for (int j = 0; j < NJ; ++j) {
      const int col = gn + j * 16;
      float sc = 1.f, off = 0.f;
      if constexpr (MODE == 1) {
        float g = bn[col], bb3 = bn[N + col], mm = bn[2 * N + col], vv = bn[3 * N + col];
        sc = g / sqrtf(vv + 1e-5f);
        off = bb3 - mm * sc;
      }
#pragma unroll
      for (int i = 0; i < MI; ++i)
#pragma unroll
        for (int e = 0; e < 4; ++e) {
          float v = acc[i][j][e];
          if constexpr (MODE == 1) v = fmaxf(fmaf(v, sc, off), 0.f);
          Cb[(long)(gm + i * 16 + e) * ldC + col] = f2bf(v);
        }
    }
  }
}

// ---------------------------------------------------------------------------
// Row softmax in place on bf16 [rows][C=4096], one block per row, normalized.
// ---------------------------------------------------------------------------
__global__ __launch_bounds__(256) void softmax_row(unsigned short* __restrict__ E, int C)
{
  const long row = blockIdx.x;
  unsigned short* p = E + row * (long)C;
  const int tid = threadIdx.x;
  u16x8 u0 = *(const u16x8*)(p + tid * 16);
  u16x8 u1 = *(const u16x8*)(p + tid * 16 + 8);
  float v[16];
#pragma unroll
  for (int e = 0; e < 8; ++e) { v[e] = bf2f(u0[e]); v[8 + e] = bf2f(u1[e]); }
  float m = v[0];
#pragma unroll
  for (int e = 1; e < 16; ++e) m = fmaxf(m, v[e]);
#pragma unroll
  for (int o = 32; o >= 1; o >>= 1) m = fmaxf(m, __shfl_xor(m, o, 64));
  __shared__ float sm[4], ss[4];
  const int wv = tid >> 6, ln = tid & 63;
  if (ln == 0) sm[wv] = m;
  __syncthreads();
  m = fmaxf(fmaxf(sm[0], sm[1]), fmaxf(sm[2], sm[3]));
  float ev[16];
  float s = 0.f;
#pragma unroll
  for (int e = 0; e < 16; ++e) { ev[e] = __expf(v[e] - m); s += ev[e]; }
#pragma unroll
  for (int o = 32; o >= 1; o >>= 1) s += __shfl_xor(s, o, 64);
  if (ln == 0) ss[wv] = s;
  __syncthreads();
  s = ss[0] + ss[1] + ss[2] + ss[3];
  const float rs = 1.0f / s;
  u16x8 o0, o1;
#pragma unroll
  for (int e = 0; e < 8; ++e) { o0[e] = f2bf(ev[e] * rs); o1[e] = f2bf(ev[8 + e] * rs); }
  *(u16x8*)(p + tid * 16) = o0;
  *(u16x8*)(p + tid * 16 + 8) = o1;
}

// ---------------------------------------------------------------------------
// Transposes (64x64 LDS tiles) + f32->bf16 convert
// ---------------------------------------------------------------------------
__global__ __launch_bounds__(256) void tr_f32_bf16(
    const float* __restrict__ src, unsigned short* __restrict__ dst, int R, int C)
{
  __shared__ float t[64][65];
  const int c0 = blockIdx.x * 64, r0 = blockIdx.y * 64;
  const long bo = (long)blockIdx.z * R * C;
  const int tc = (threadIdx.x & 15) * 4;
  const int tr = threadIdx.x >> 4;
#pragma unroll
  for (int i = 0; i < 4; ++i) {
    const int r = tr + i * 16;
    float4 v = *(const float4*)&src[bo + (long)(r0 + r) * C + c0 + tc];
    t[r][tc] = v.x; t[r][tc + 1] = v.y; t[r][tc + 2] = v.z; t[r][tc + 3] = v.w;
  }
  __syncthreads();
#pragma unroll
  for (int i = 0; i < 4; ++i) {
    const int c = tr + i * 16;
    u16x4 o;
#pragma unroll
    for (int k = 0; k < 4; ++k) o[k] = f2bf(t[tc + k][c]);
    *(u16x4*)&dst[bo + (long)(c0 + c) * R + r0 + tc] = o;
  }
}

__global__ __launch_bounds__(256) void tr_bf16(
    const unsigned short* __restrict__ src, unsigned short* __restrict__ dst, int R, int C)
{
  __shared__ unsigned short t[64][68];
  const int c0 = blockIdx.x * 64, r0 = blockIdx.y * 64;
  const long bo = (long)blockIdx.z * R * C;
  const int tc = (threadIdx.x & 15) * 4;
  const int tr = threadIdx.x >> 4;
#pragma unroll
  for (int i = 0; i < 4; ++i) {
    const int r = tr + i * 16;
    u16x4 v = *(const u16x4*)&src[bo + (long)(r0 + r) * C + c0 + tc];
    t[r][tc] = v[0]; t[r][tc + 1] = v[1]; t[r][tc + 2] = v[2]; t[r][tc + 3] = v[3];
  }
  __syncthreads();
#pragma unroll
  for (int i = 0; i < 4; ++i) {
    const int c = tr + i * 16;
    u16x4 o;
#pragma unroll
    for (int k = 0; k < 4; ++k) o[k] = t[tc + k][c];
    *(u16x4*)&dst[bo + (long)(c0 + c) * R + r0 + tc] = o;
  }
}

__global__ __launch_bounds__(256) void cvt_bf16(
    const float* __restrict__ s, unsigned short* __restrict__ d, long n)
{
  long i = ((long)blockIdx.x * 256 + threadIdx.x) * 4;
  if (i >= n) return;
  float4 v = *(const float4*)(s + i);
  u16x4 o;
  o[0] = f2bf(v.x); o[1] = f2bf(v.y); o[2] = f2bf(v.z); o[3] = f2bf(v.w);
  *(u16x4*)(d + i) = o;
}

// ---------------------------------------------------------------------------
extern "C" void kernel_launch(void* const* d_in, const int* in_sizes, int n_in,
                              void* d_out, int out_size, void* d_ws, size_t ws_size,
                              hipStream_t stream)
{
  const int NB = 2, CIN = 2048, HW = 4096, RC = 512, CT = 4096;
  const float* x = (const float*)d_in[0];

  char* wsb = (char*)d_ws;
  unsigned short* xT      = (unsigned short*)wsb;                 // [NB][HW][CIN]  32MB
  unsigned short* redT    = (unsigned short*)(wsb + 33554432);    // [NB][HW][RC]    8MB
  unsigned short* red     = (unsigned short*)(wsb + 41943040);    // [NB][RC][HW]    8MB
  unsigned short* a1T     = (unsigned short*)(wsb + 50331648);    // [NB][HW][RC]    8MB
  unsigned short* logitsT = (unsigned short*)(wsb + 58720256);    // [NB][HW][CT]   64MB
  unsigned short* wredb   = (unsigned short*)(wsb + 125829120);   // [RC][CIN]       2MB
  unsigned short* w1b     = (unsigned short*)(wsb + 127926272);   // [RC][RC]      0.5MB
  unsigned short* w2b     = (unsigned short*)(wsb + 128450560);   // [CT][RC]        4MB

  // x [NB][CIN][HW] f32 -> xT [NB][HW][CIN] bf16 (once)
  tr_f32_bf16<<<dim3(HW / 64, CIN / 64, NB), 256, 0, stream>>>(x, xT, CIN, HW);

  for (int br = 0; br < 2; ++br) {
    const float* w_red = (const float*)d_in[1 + br * 5 + 0];
    const float* bn1f  = (const float*)d_in[1 + br * 5 + 1];
    const float* w1f   = (const float*)d_in[1 + br * 5 + 2];
    const float* bn2f  = (const float*)d_in[1 + br * 5 + 3];
    const float* w2f   = (const float*)d_in[1 + br * 5 + 4];

    cvt_bf16<<<dim3(1024), 256, 0, stream>>>(w_red, wredb, (long)RC * CIN);
    cvt_bf16<<<dim3(256),  256, 0, stream>>>(w1f,   w1b,   (long)RC * RC);
    cvt_bf16<<<dim3(2048), 256, 0, stream>>>(w2f,   w2b,   (long)CT * RC);

    // G1: redT[t][r] = relu(bn1(sum_k xT[t][k] * Wred[r][k]))   M=HW,N=RC,K=CIN
    gemm_mfma<128, 128, 2, 2, 1><<<dim3(RC / 128, HW / 128, NB), 256, 0, stream>>>(
        xT, (long)HW * CIN, wredb, 0, redT, (long)HW * RC, RC, HW, RC, CIN, bn1f);

    // red = transpose(redT)  -> [NB][RC][HW] (bmm A-operand)
    tr_bf16<<<dim3(RC / 64, HW / 64, NB), 256, 0, stream>>>(redT, red, HW, RC);

    // G2: a1T[t][r] = relu(bn2(sum_k redT[t][k] * W1[r][k]))    M=HW,N=RC,K=RC
    gemm_mfma<128, 128, 2, 2, 1><<<dim3(RC / 128, HW / 128, NB), 256, 0, stream>>>(
        redT, (long)HW * RC, w1b, 0, a1T, (long)HW * RC, RC, HW, RC, RC, bn2f);

    // G3: logitsT[t][c] = sum_k a1T[t][k] * W2[c][k]            M=HW,N=CT,K=RC
    gemm_mfma<256, 256, 2, 4, 0><<<dim3(CT / 256, HW / 256, NB), 512, 0, stream>>>(
        a1T, (long)HW * RC, w2b, 0, logitsT, (long)HW * CT, CT, HW, CT, RC, nullptr);

    // row softmax over c, normalized, in place -> E^T (the bmm B-operand)
    softmax_row<<<dim3(NB * HW), 256, 0, stream>>>(logitsT, CT);

    // G4: out[n][br*RC+r][t] = sum_k red[r][k] * ET[t][k]       M=RC,N=HW,K=CT
    gemm_mfma<128, 128, 2, 2, 2><<<dim3(HW / 128, RC / 128, NB), 256, 0, stream>>>(
        red, (long)RC * HW, logitsT, (long)HW * CT,
        (float*)d_out + (long)br * RC * HW, (long)2 * RC * HW, HW,
        RC, HW, CT, nullptr);
  }
}

// Round 4
// 473.379 us; speedup vs baseline: 1.0021x; 1.0021x over previous
//
#include <hip/hip_runtime.h>
#include <hip/hip_bf16.h>

typedef __attribute__((ext_vector_type(8))) short bf16x8;
typedef __attribute__((ext_vector_type(4))) float f32x4;
typedef __attribute__((ext_vector_type(4))) unsigned short u16x4;
typedef __attribute__((ext_vector_type(8))) unsigned short u16x8;
typedef __attribute__((ext_vector_type(4))) unsigned u32x4;

__device__ __forceinline__ unsigned short f2bf(float f) {
  unsigned u = __float_as_uint(f);
  u += 0x7FFF + ((u >> 16) & 1);   // RNE
  return (unsigned short)(u >> 16);
}
__device__ __forceinline__ float bf2f(unsigned short h) {
  return __uint_as_float(((unsigned)h) << 16);
}

__device__ __forceinline__ void gll16(const void* g, void* l) {
  __builtin_amdgcn_global_load_lds(
      (const __attribute__((address_space(1))) void*)g,
      (__attribute__((address_space(3))) void*)l, 16, 0, 0);
}

// ---------------------------------------------------------------------------
// bf16 MFMA GEMM:  C[bz] = A[bz] (MxK, k-inner) * B[bz]^T  (B is [N][K] k-inner)
// Tile BM x BN, BK=32, WM x WN waves. Ring-4 LDS, depth-2 prefetch with
// counted vmcnt, TWO phases per subtile (m201-style: reads+stage | barrier |
// lgkmcnt(0)+sched_barrier | setprio+MFMA cluster | barrier).
// LDS swizzle: rows paired into 128B lines, 16B slot XOR (line&7)  -> 0 confl.
// Epilogue: acc -> LDS re-tile (reuses ring) -> coalesced b128 stores.
// MODE 0: bf16 store. MODE 1: per-COLUMN BN (bn=[4][N]) + ReLU, bf16 store.
// MODE 2: fp32 store.  Requires M%BM==0, N%BN==0, K%32==0, K/32 >= 2,
// gridDim.x*gridDim.y % 8 == 0.
// ---------------------------------------------------------------------------
template <int BM, int BN, int WM, int WN, int MODE>
__global__ __launch_bounds__(WM* WN * 64) void gemm_mfma(
    const unsigned short* __restrict__ A, long abs_,
    const unsigned short* __restrict__ B, long bbs,
    void* __restrict__ Cv, long cbs, int ldC,
    int M, int N, int K,
    const float* __restrict__ bn)
{
  constexpr int T = WM * WN * 64;
  constexpr int WTM = BM / WM, WTN = BN / WN;
  constexpr int MI = WTM / 16, NJ = WTN / 16, MIP = MI / 2;
  constexpr int SLOT = (BM + BN) * 64;        // bytes per ring slot
  constexpr int CA = BM * 4 / T;              // A 16B-chunks per thread
  constexpr int CB = BN * 4 / T;
  constexpr int EPITCH = (MODE == 2 ? BN * 4 : BN * 2) + 16;  // epi row bytes
  constexpr int EPIB = 128 * EPITCH;
  constexpr int SMEM = (4 * SLOT > EPIB) ? 4 * SLOT : EPIB;
  __shared__ char smem[SMEM];

  const int tid = threadIdx.x;
  const int w = tid >> 6, lane = tid & 63;
  const int wr = w / WN, wc = w % WN;
  const int llo = lane & 15, lhi = lane >> 4;
  const int bz = blockIdx.z;

  // bijective XCD-aware swizzle (nwg % 8 == 0 for all our grids)
  const int gx = gridDim.x;
  const int nwg = gx * gridDim.y;
  const int orig = blockIdx.y * gx + blockIdx.x;
  const int sw = (orig & 7) * (nwg >> 3) + (orig >> 3);
  const int m0 = (sw / gx) * BM, n0 = (sw % gx) * BN;

  const unsigned short* Ab = A + (long)bz * abs_;
  const unsigned short* Bb = B + (long)bz * bbs;
  const int NT = K >> 5;

  // staging descriptors (inverse-swizzled global src, linear LDS dst)
  long aoff[CA]; int adst[CA];
#pragma unroll
  for (int i = 0; i < CA; ++i) {
    int g = i * T + tid;
    int line = g >> 3, ph = g & 7;
    int t8 = ph ^ (line & 7);
    int row = line * 2 + (t8 >> 2);
    aoff[i] = (long)(m0 + row) * K + (t8 & 3) * 8;
    adst[i] = g * 16;
  }
  long boff[CB]; int bdst[CB];
#pragma unroll
  for (int i = 0; i < CB; ++i) {
    int g = i * T + tid;
    int line = g >> 3, ph = g & 7;
    int t8 = ph ^ (line & 7);
    int row = line * 2 + (t8 >> 2);
    boff[i] = (long)(n0 + row) * K + (t8 & 3) * 8;
    bdst[i] = g * 16;
  }

  // swizzled ds_read byte offsets, loop-invariant
  int aro[MI];
#pragma unroll
  for (int i = 0; i < MI; ++i) {
    int row = wr * WTM + i * 16 + llo;
    int line = row >> 1;
    int ph = (lhi + ((row & 1) << 2)) ^ (line & 7);
    aro[i] = line * 128 + ph * 16;
  }
  int bro[NJ];
#pragma unroll
  for (int j = 0; j < NJ; ++j) {
    int col = wc * WTN + j * 16 + llo;
    int line = col >> 1;
    int ph = (lhi + ((col & 1) << 2)) ^ (line & 7);
    bro[j] = line * 128 + ph * 16;
  }

  auto stageA = [&](int t) {
    const long ko = (long)t * 32;
    char* ab = smem + (t & 3) * SLOT;
#pragma unroll
    for (int i = 0; i < CA; ++i) gll16(Ab + aoff[i] + ko, ab + adst[i]);
  };
  auto stageB = [&](int t) {
    const long ko = (long)t * 32;
    char* bb2 = smem + (t & 3) * SLOT + BM * 64;
#pragma unroll
    for (int i = 0; i < CB; ++i) gll16(Bb + boff[i] + ko, bb2 + bdst[i]);
  };

  f32x4 acc[MI][NJ];
#pragma unroll
  for (int i = 0; i < MI; ++i)
#pragma unroll
    for (int j = 0; j < NJ; ++j) acc[i][j] = (f32x4)0.f;

  stageA(0); stageB(0); stageA(1); stageB(1);
  asm volatile("s_waitcnt vmcnt(4)" ::: "memory");   // slot 0 landed
  __builtin_amdgcn_s_barrier();
  asm volatile("" ::: "memory");

  for (int t = 0; t < NT; ++t) {
    char* ab = smem + (t & 3) * SLOT;
    char* bb2 = ab + BM * 64;
    bf16x8 afA[MIP], afB[MIP], bfr[NJ];
    // ---------------- Phase 1: A rows [0, MIP*16) x all B ----------------
#pragma unroll
    for (int i = 0; i < MIP; ++i) afA[i] = *(const bf16x8*)(ab + aro[i]);
#pragma unroll
    for (int j = 0; j < NJ; ++j) bfr[j] = *(const bf16x8*)(bb2 + bro[j]);
    if (t + 2 < NT) stageA(t + 2);
    __builtin_amdgcn_s_barrier();
    asm volatile("s_waitcnt lgkmcnt(0)" ::: "memory");
    __builtin_amdgcn_sched_barrier(0);
    __builtin_amdgcn_s_setprio(1);
#pragma unroll
    for (int i = 0; i < MIP; ++i)
#pragma unroll
      for (int j = 0; j < NJ; ++j)
        acc[i][j] = __builtin_amdgcn_mfma_f32_16x16x32_bf16(afA[i], bfr[j], acc[i][j], 0, 0, 0);
    __builtin_amdgcn_s_setprio(0);
    __builtin_amdgcn_sched_barrier(0);
    __builtin_amdgcn_s_barrier();
    // ---------------- Phase 2: A rows [MIP*16, MI*16) x all B ------------
#pragma unroll
    for (int i = 0; i < MIP; ++i) afB[i] = *(const bf16x8*)(ab + aro[MIP + i]);
    if (t + 2 < NT) stageB(t + 2);
    __builtin_amdgcn_s_barrier();
    asm volatile("s_waitcnt lgkmcnt(0)" ::: "memory");
    __builtin_amdgcn_sched_barrier(0);
    __builtin_amdgcn_s_setprio(1);
#pragma unroll
    for (int i = 0; i < MIP; ++i)
#pragma unroll
      for (int j = 0; j < NJ; ++j)
        acc[MIP + i][j] = __builtin_amdgcn_mfma_f32_16x16x32_bf16(afB[i], bfr[j], acc[MIP + i][j], 0, 0, 0);
    __builtin_amdgcn_s_setprio(0);
    __builtin_amdgcn_sched_barrier(0);
    // counted vmcnt once per subtile: drain slot t+1, keep t+2's 4 in flight
    if (t + 2 < NT) {
      asm volatile("s_waitcnt vmcnt(4)" ::: "memory");
    } else if (t + 1 < NT) {
      asm volatile("s_waitcnt vmcnt(0)" ::: "memory");
    }
    __builtin_amdgcn_s_barrier();
    asm volatile("" ::: "memory");
  }
  asm volatile("" ::: "memory");

  // ---------------- epilogue: LDS re-tile -> coalesced b128 stores -------
  constexpr int HALVES = BM / 128;
  float scj[NJ], offj[NJ];
  if constexpr (MODE == 1) {
#pragma unroll
    for (int j = 0; j < NJ; ++j) {
      int col = n0 + wc * WTN + j * 16 + llo;
      float g = bn[col], b2 = bn[N + col], mm = bn[2 * N + col], vv = bn[3 * N + col];
      scj[j] = g / sqrtf(vv + 1e-5f);
      offj[j] = b2 - mm * scj[j];
    }
  }
  float* Cf = (float*)Cv;
  unsigned short* Ch = (unsigned short*)Cv;
#pragma unroll
  for (int h = 0; h < HALVES; ++h) {
    if (HALVES == 1 || wr == h) {
      const int rbase = (HALVES == 1 ? wr * WTM : 0) + lhi * 4;
#pragma unroll
      for (int i = 0; i < MI; ++i) {
#pragma unroll
        for (int j = 0; j < NJ; ++j) {
          const int cloc = wc * WTN + j * 16 + llo;
#pragma unroll
          for (int e = 0; e < 4; ++e) {
            float v = acc[i][j][e];
            if constexpr (MODE == 1) v = fmaxf(fmaf(v, scj[j], offj[j]), 0.f);
            if constexpr (MODE == 2)
              *(float*)(smem + (rbase + i * 16 + e) * EPITCH + cloc * 4) = v;
            else
              *(unsigned short*)(smem + (rbase + i * 16 + e) * EPITCH + cloc * 2) = f2bf(v);
          }
        }
      }
    }
    asm volatile("" ::: "memory");
    __builtin_amdgcn_s_barrier();
    asm volatile("" ::: "memory");
    constexpr int CPR = (MODE == 2 ? BN * 4 : BN * 2) / 16;  // 16B chunks/row
    constexpr int NCH = 128 * CPR / T;
#pragma unroll
    for (int c = 0; c < NCH; ++c) {
      int idx = c * T + tid;
      int row = idx / CPR, cc = idx % CPR;
      u32x4 val = *(const u32x4*)(smem + row * EPITCH + cc * 16);
      long grow = m0 + h * 128 + row;
      if constexpr (MODE == 2)
        *(u32x4*)&Cf[(long)bz * cbs + grow * ldC + n0 + cc * 4] = val;
      else
        *(u32x4*)&Ch[(long)bz * cbs + grow * ldC + n0 + cc * 8] = val;
    }
    if (h + 1 < HALVES) {
      asm volatile("" ::: "memory");
      __builtin_amdgcn_s_barrier();
      asm volatile("" ::: "memory");
    }
  }
}

// ---------------------------------------------------------------------------
// Row softmax in place on bf16 [rows][C=4096], one block per row, normalized.
// ---------------------------------------------------------------------------
__global__ __launch_bounds__(256) void softmax_row(unsigned short* __restrict__ E, int C)
{
  const long row = blockIdx.x;
  unsigned short* p = E + row * (long)C;
  const int tid = threadIdx.x;
  u16x8 u0 = *(const u16x8*)(p + tid * 16);
  u16x8 u1 = *(const u16x8*)(p + tid * 16 + 8);
  float v[16];
#pragma unroll
  for (int e = 0; e < 8; ++e) { v[e] = bf2f(u0[e]); v[8 + e] = bf2f(u1[e]); }
  float m = v[0];
#pragma unroll
  for (int e = 1; e < 16; ++e) m = fmaxf(m, v[e]);
#pragma unroll
  for (int o = 32; o >= 1; o >>= 1) m = fmaxf(m, __shfl_xor(m, o, 64));
  __shared__ float sm[4], ss[4];
  const int wv = tid >> 6, ln = tid & 63;
  if (ln == 0) sm[wv] = m;
  __syncthreads();
  m = fmaxf(fmaxf(sm[0], sm[1]), fmaxf(sm[2], sm[3]));
  float ev[16];
  float s = 0.f;
#pragma unroll
  for (int e = 0; e < 16; ++e) { ev[e] = __expf(v[e] - m); s += ev[e]; }
#pragma unroll
  for (int o = 32; o >= 1; o >>= 1) s += __shfl_xor(s, o, 64);
  if (ln == 0) ss[wv] = s;
  __syncthreads();
  s = ss[0] + ss[1] + ss[2] + ss[3];
  const float rs = 1.0f / s;
  u16x8 o0, o1;
#pragma unroll
  for (int e = 0; e < 8; ++e) { o0[e] = f2bf(ev[e] * rs); o1[e] = f2bf(ev[8 + e] * rs); }
  *(u16x8*)(p + tid * 16) = o0;
  *(u16x8*)(p + tid * 16 + 8) = o1;
}

// ---------------------------------------------------------------------------
// Transposes (64x64 LDS tiles) + weight convert (3 tensors in one dispatch)
// ---------------------------------------------------------------------------
__global__ __launch_bounds__(256) void tr_f32_bf16(
    const float* __restrict__ src, unsigned short* __restrict__ dst, int R, int C)
{
  __shared__ float t[64][65];
  const int c0 = blockIdx.x * 64, r0 = blockIdx.y * 64;
  const long bo = (long)blockIdx.z * R * C;
  const int tc = (threadIdx.x & 15) * 4;
  const int tr = threadIdx.x >> 4;
#pragma unroll
  for (int i = 0; i < 4; ++i) {
    const int r = tr + i * 16;
    float4 v = *(const float4*)&src[bo + (long)(r0 + r) * C + c0 + tc];
    t[r][tc] = v.x; t[r][tc + 1] = v.y; t[r][tc + 2] = v.z; t[r][tc + 3] = v.w;
  }
  __syncthreads();
#pragma unroll
  for (int i = 0; i < 4; ++i) {
    const int c = tr + i * 16;
    u16x4 o;
#pragma unroll
    for (int k = 0; k < 4; ++k) o[k] = f2bf(t[tc + k][c]);
    *(u16x4*)&dst[bo + (long)(c0 + c) * R + r0 + tc] = o;
  }
}

__global__ __launch_bounds__(256) void tr_bf16(
    const unsigned short* __restrict__ src, unsigned short* __restrict__ dst, int R, int C)
{
  __shared__ unsigned short t[64][68];
  const int c0 = blockIdx.x * 64, r0 = blockIdx.y * 64;
  const long bo = (long)blockIdx.z * R * C;
  const int tc = (threadIdx.x & 15) * 4;
  const int tr = threadIdx.x >> 4;
#pragma unroll
  for (int i = 0; i < 4; ++i) {
    const int r = tr + i * 16;
    u16x4 v = *(const u16x4*)&src[bo + (long)(r0 + r) * C + c0 + tc];
    t[r][tc] = v[0]; t[r][tc + 1] = v[1]; t[r][tc + 2] = v[2]; t[r][tc + 3] = v[3];
  }
  __syncthreads();
#pragma unroll
  for (int i = 0; i < 4; ++i) {
    const int c = tr + i * 16;
    u16x4 o;
#pragma unroll
    for (int k = 0; k < 4; ++k) o[k] = t[tc + k][c];
    *(u16x4*)&dst[bo + (long)(c0 + c) * R + r0 + tc] = o;
  }
}

__global__ __launch_bounds__(256) void cvt3(
    const float* __restrict__ s0, unsigned short* __restrict__ d0, long n0,
    const float* __restrict__ s1, unsigned short* __restrict__ d1, long n1,
    const float* __restrict__ s2, unsigned short* __restrict__ d2, long n2)
{
  long i = ((long)blockIdx.x * 256 + threadIdx.x) * 4;
  const float* s; unsigned short* d; long off;
  if (i < n0) { s = s0; d = d0; off = i; }
  else if (i < n0 + n1) { s = s1; d = d1; off = i - n0; }
  else if (i < n0 + n1 + n2) { s = s2; d = d2; off = i - n0 - n1; }
  else return;
  float4 v = *(const float4*)(s + off);
  u16x4 o;
  o[0] = f2bf(v.x); o[1] = f2bf(v.y); o[2] = f2bf(v.z); o[3] = f2bf(v.w);
  *(u16x4*)(d + off) = o;
}

// ---------------------------------------------------------------------------
extern "C" void kernel_launch(void* const* d_in, const int* in_sizes, int n_in,
                              void* d_out, int out_size, void* d_ws, size_t ws_size,
                              hipStream_t stream)
{
  const int NB = 2, CIN = 2048, HW = 4096, RC = 512, CT = 4096;
  const float* x = (const float*)d_in[0];

  char* wsb = (char*)d_ws;
  unsigned short* xT      = (unsigned short*)wsb;                 // [NB][HW][CIN]  32MB
  unsigned short* redT    = (unsigned short*)(wsb + 33554432);    // [NB][HW][RC]    8MB
  unsigned short* red     = (unsigned short*)(wsb + 41943040);    // [NB][RC][HW]    8MB
  unsigned short* a1T     = (unsigned short*)(wsb + 50331648);    // [NB][HW][RC]    8MB
  unsigned short* logitsT = (unsigned short*)(wsb + 58720256);    // [NB][HW][CT]   64MB
  unsigned short* wredb   = (unsigned short*)(wsb + 125829120);   // [RC][CIN]       2MB
  unsigned short* w1b     = (unsigned short*)(wsb + 127926272);   // [RC][RC]      0.5MB
  unsigned short* w2b     = (unsigned short*)(wsb + 128450560);   // [CT][RC]        4MB

  // x [NB][CIN][HW] f32 -> xT [NB][HW][CIN] bf16 (once)
  tr_f32_bf16<<<dim3(HW / 64, CIN / 64, NB), 256, 0, stream>>>(x, xT, CIN, HW);

  const long nw0 = (long)RC * CIN, nw1 = (long)RC * RC, nw2 = (long)CT * RC;
  const int cvtBlocks = (int)((nw0 + nw1 + nw2) / 4 / 256);

  for (int br = 0; br < 2; ++br) {
    const float* w_red = (const float*)d_in[1 + br * 5 + 0];
    const float* bn1f  = (const float*)d_in[1 + br * 5 + 1];
    const float* w1f   = (const float*)d_in[1 + br * 5 + 2];
    const float* bn2f  = (const float*)d_in[1 + br * 5 + 3];
    const float* w2f   = (const float*)d_in[1 + br * 5 + 4];

    cvt3<<<dim3(cvtBlocks), 256, 0, stream>>>(
        w_red, wredb, nw0, w1f, w1b, nw1, w2f, w2b, nw2);

    // G1: redT[t][r] = relu(bn1(sum_k xT[t][k] * Wred[r][k]))   M=HW,N=RC,K=CIN
    gemm_mfma<128, 128, 2, 2, 1><<<dim3(RC / 128, HW / 128, NB), 256, 0, stream>>>(
        xT, (long)HW * CIN, wredb, 0, redT, (long)HW * RC, RC, HW, RC, CIN, bn1f);

    // red = transpose(redT)  -> [NB][RC][HW] (bmm A-operand)
    tr_bf16<<<dim3(RC / 64, HW / 64, NB), 256, 0, stream>>>(redT, red, HW, RC);

    // G2: a1T[t][r] = relu(bn2(sum_k redT[t][k] * W1[r][k]))    M=HW,N=RC,K=RC
    gemm_mfma<128, 128, 2, 2, 1><<<dim3(RC / 128, HW / 128, NB), 256, 0, stream>>>(
        redT, (long)HW * RC, w1b, 0, a1T, (long)HW * RC, RC, HW, RC, RC, bn2f);

    // G3: logitsT[t][c] = sum_k a1T[t][k] * W2[c][k]            M=HW,N=CT,K=RC
    gemm_mfma<256, 256, 2, 4, 0><<<dim3(CT / 256, HW / 256, NB), 512, 0, stream>>>(
        a1T, (long)HW * RC, w2b, 0, logitsT, (long)HW * CT, CT, HW, CT, RC, nullptr);

    // row softmax over c, normalized, in place -> E^T (the bmm B-operand)
    softmax_row<<<dim3(NB * HW), 256, 0, stream>>>(logitsT, CT);

    // G4: out[n][br*RC+r][t] = sum_k red[r][k] * ET[t][k]       M=RC,N=HW,K=CT
    gemm_mfma<128, 128, 2, 2, 2><<<dim3(HW / 128, RC / 128, NB), 256, 0, stream>>>(
        red, (long)RC * HW, logitsT, (long)HW * CT,
        (float*)d_out + (long)br * RC * HW, (long)2 * RC * HW, HW,
        RC, HW, CT, nullptr);
  }
}

// Round 7
// 451.939 us; speedup vs baseline: 1.0496x; 1.0474x over previous
//
#include <hip/hip_runtime.h>
#include <hip/hip_bf16.h>

typedef __attribute__((ext_vector_type(8))) short bf16x8;
typedef __attribute__((ext_vector_type(4))) float f32x4;
typedef __attribute__((ext_vector_type(4))) unsigned short u16x4;
typedef __attribute__((ext_vector_type(8))) unsigned short u16x8;
typedef __attribute__((ext_vector_type(4))) unsigned u32x4;

__device__ __forceinline__ unsigned short f2bf(float f) {
  unsigned u = __float_as_uint(f);
  u += 0x7FFF + ((u >> 16) & 1);   // RNE
  return (unsigned short)(u >> 16);
}
__device__ __forceinline__ float bf2f(unsigned short h) {
  return __uint_as_float(((unsigned)h) << 16);
}

__device__ __forceinline__ void gll16(const void* g, void* l) {
  __builtin_amdgcn_global_load_lds(
      (const __attribute__((address_space(1))) void*)g,
      (__attribute__((address_space(3))) void*)l, 16, 0, 0);
}

// ---------------------------------------------------------------------------
// bf16 MFMA GEMM, 8 waves (512 thr):  C[bz] = A[bz] (MxK k-inner) * B[bz]^T
// (B is [N][K] k-inner).  Tile BM x 128, BK=64, waves 2(M) x 4(N).
// Ring-3 LDS slots, depth-2 prefetch, counted vmcnt (never 0 mid-loop).
// 2 phases per K-tile: {ds_read ks | stage half | barrier | lgkm0+schedbar |
// setprio+MFMA | barrier}.
// LDS: 128B per row (BK=64 bf16); 16B slot s stored at phys s^(row&7);
// staged linearly with inverse-swizzled global source (rule #21) -> 0 confl.
// Epilogue: acc -> LDS re-tile -> coalesced 16B stores.
// MODE 0: bf16 store. MODE 1: per-COLUMN BN (bn=[4][N]) + ReLU, bf16 store.
// MODE 2: fp32 store.
// Requires M%BM==0, N%128==0, K%64==0, K/64>=2, (gridDim.x*gridDim.y)%8==0.
// ---------------------------------------------------------------------------
template <int BM, int MODE>
__global__ __launch_bounds__(512, 2) void gemm8w(
    const unsigned short* __restrict__ A, long abs_,
    const unsigned short* __restrict__ B, long bbs,
    void* __restrict__ Cv, long cbs, int ldC,
    int M, int N, int K,
    const float* __restrict__ bn)
{
  constexpr int BN = 128;
  constexpr int WTM = BM / 2, WTN = 32;
  constexpr int MI = WTM / 16, NJ = 2;
  constexpr int SLOT = (BM + BN) * 128;   // bytes per ring slot
  constexpr int AOFS = BM * 128;          // B region offset within slot
  constexpr int CA = BM / 64, CB = 2;     // 16B chunks per thread (A, B)
  constexpr int CT_ = CA + CB, HT = CT_ / 2;
  constexpr int EPITCH = (MODE == 2 ? BN * 4 : BN * 2) + 16;
  constexpr int EPIB = 128 * EPITCH;
  constexpr int SMEM = (3 * SLOT > EPIB) ? 3 * SLOT : EPIB;
  __shared__ char smem[SMEM];

  const int tid = threadIdx.x;
  const int w = tid >> 6, lane = tid & 63;
  const int wr = w >> 2, wc = w & 3;      // 2 x 4 waves
  const int llo = lane & 15, lhi = lane >> 4;
  const int bz = blockIdx.z;

  // bijective XCD-aware swizzle (nwg % 8 == 0 for all our grids)
  const int gx = gridDim.x;
  const int nwg = gx * gridDim.y;
  const int orig = blockIdx.y * gx + blockIdx.x;
  const int sw = (orig & 7) * (nwg >> 3) + (orig >> 3);
  const int m0 = (sw / gx) * BM, n0 = (sw % gx) * BN;

  const unsigned short* Ab = A + (long)bz * abs_;
  const unsigned short* Bb = B + (long)bz * bbs;
  const int NT = K >> 6;

  // staging descriptors: chunk c handles 16B; inverse-swizzled global source,
  // linear LDS destination (wave-uniform base + lane*16)
  const unsigned short* gsrc[CT_];
  long gofs[CT_];
  int ldst[CT_];
#pragma unroll
  for (int c = 0; c < CT_; ++c) {
    int g = (c < CA ? c : c - CA) * 512 + tid;
    int row = g >> 3, ph = g & 7;
    int s = ph ^ (row & 7);
    if (c < CA) {
      gsrc[c] = Ab; gofs[c] = (long)(m0 + row) * K + s * 8; ldst[c] = g * 16;
    } else {
      gsrc[c] = Bb; gofs[c] = (long)(n0 + row) * K + s * 8; ldst[c] = AOFS + g * 16;
    }
  }

  // swizzled ds_read byte offsets (ks=0; ks=1 is ^64)
  int aro[MI];
#pragma unroll
  for (int i = 0; i < MI; ++i) {
    int row = wr * WTM + i * 16 + llo;
    aro[i] = row * 128 + (lhi ^ (row & 7)) * 16;
  }
  int bro[NJ];
#pragma unroll
  for (int j = 0; j < NJ; ++j) {
    int col = wc * WTN + j * 16 + llo;
    bro[j] = AOFS + col * 128 + (lhi ^ (col & 7)) * 16;
  }

  auto stage = [&](int t, int slot, int h) {
    const long ko = (long)t * 64;
    char* base = smem + slot * SLOT;
#pragma unroll
    for (int c = 0; c < HT; ++c) {
      int cc = h * HT + c;
      gll16(gsrc[cc] + gofs[cc] + ko, base + ldst[cc]);
    }
  };

  f32x4 acc[MI][NJ];
#pragma unroll
  for (int i = 0; i < MI; ++i)
#pragma unroll
    for (int j = 0; j < NJ; ++j) acc[i][j] = (f32x4)0.f;

  stage(0, 0, 0); stage(0, 0, 1);
  stage(1, 1, 0); stage(1, 1, 1);
  if constexpr (CT_ == 4) asm volatile("s_waitcnt vmcnt(4)" ::: "memory");
  else                    asm volatile("s_waitcnt vmcnt(6)" ::: "memory");
  __builtin_amdgcn_s_barrier();
  asm volatile("" ::: "memory");

  int cur = 0;
  for (int t = 0; t < NT; ++t) {
    char* base = smem + cur * SLOT;
    const int nslot = (cur + 2 >= 3) ? cur - 1 : cur + 2;
#pragma unroll
    for (int ks = 0; ks < 2; ++ks) {
      bf16x8 af[MI], bf[NJ];
#pragma unroll
      for (int i = 0; i < MI; ++i) af[i] = *(const bf16x8*)(base + (aro[i] ^ (ks * 64)));
#pragma unroll
      for (int j = 0; j < NJ; ++j) bf[j] = *(const bf16x8*)(base + (bro[j] ^ (ks * 64)));
      if (t + 2 < NT) stage(t + 2, nslot, ks);
      __builtin_amdgcn_s_barrier();
      asm volatile("s_waitcnt lgkmcnt(0)" ::: "memory");
      __builtin_amdgcn_sched_barrier(0);
      __builtin_amdgcn_s_setprio(1);
#pragma unroll
      for (int i = 0; i < MI; ++i)
#pragma unroll
        for (int j = 0; j < NJ; ++j)
          acc[i][j] = __builtin_amdgcn_mfma_f32_16x16x32_bf16(af[i], bf[j], acc[i][j], 0, 0, 0);
      __builtin_amdgcn_s_setprio(0);
      __builtin_amdgcn_sched_barrier(0);
      if (ks == 1) {
        // boundary: tile t+1 must be landed; only t+2's loads may stay in flight
        if (t + 2 < NT) {
          if constexpr (CT_ == 4) asm volatile("s_waitcnt vmcnt(4)" ::: "memory");
          else                    asm volatile("s_waitcnt vmcnt(6)" ::: "memory");
        } else if (t + 1 < NT) {
          asm volatile("s_waitcnt vmcnt(0)" ::: "memory");
        }
      }
      __builtin_amdgcn_s_barrier();
      asm volatile("" ::: "memory");
    }
    cur = (cur + 1 == 3) ? 0 : cur + 1;
  }

  // ---------------- epilogue: LDS re-tile -> coalesced stores -------------
  constexpr int HALVES = BM / 128;
  float scj[NJ], offj[NJ];
  if constexpr (MODE == 1) {
#pragma unroll
    for (int j = 0; j < NJ; ++j) {
      int col = n0 + wc * WTN + j * 16 + llo;
      float g = bn[col], b2 = bn[N + col], mm = bn[2 * N + col], vv = bn[3 * N + col];
      scj[j] = g / sqrtf(vv + 1e-5f);
      offj[j] = b2 - mm * scj[j];
    }
  }
  float* Cf = (float*)Cv;
  unsigned short* Ch = (unsigned short*)Cv;
#pragma unroll
  for (int h = 0; h < HALVES; ++h) {
    if (HALVES == 1 || wr == h) {
      const int rbase = (HALVES == 1 ? wr * WTM : 0) + lhi * 4;
#pragma unroll
      for (int i = 0; i < MI; ++i) {
#pragma unroll
        for (int j = 0; j < NJ; ++j) {
          const int cloc = wc * WTN + j * 16 + llo;
#pragma unroll
          for (int e = 0; e < 4; ++e) {
            float v = acc[i][j][e];
            if constexpr (MODE == 1) v = fmaxf(fmaf(v, scj[j], offj[j]), 0.f);
            if constexpr (MODE == 2)
              *(float*)(smem + (rbase + i * 16 + e) * EPITCH + cloc * 4) = v;
            else
              *(unsigned short*)(smem + (rbase + i * 16 + e) * EPITCH + cloc * 2) = f2bf(v);
          }
        }
      }
    }
    asm volatile("" ::: "memory");
    __builtin_amdgcn_s_barrier();
    asm volatile("" ::: "memory");
    constexpr int CPR = (MODE == 2 ? BN * 4 : BN * 2) / 16;  // 16B chunks/row
    constexpr int NCH = 128 * CPR / 512;
#pragma unroll
    for (int c = 0; c < NCH; ++c) {
      int idx = c * 512 + tid;
      int row = idx / CPR, cc = idx % CPR;
      u32x4 val = *(const u32x4*)(smem + row * EPITCH + cc * 16);
      long grow = m0 + h * 128 + row;
      if constexpr (MODE == 2)
        *(u32x4*)&Cf[(long)bz * cbs + grow * ldC + n0 + cc * 4] = val;
      else
        *(u32x4*)&Ch[(long)bz * cbs + grow * ldC + n0 + cc * 8] = val;
    }
    if (h + 1 < HALVES) {
      asm volatile("" ::: "memory");
      __builtin_amdgcn_s_barrier();
      asm volatile("" ::: "memory");
    }
  }
}

// ---------------------------------------------------------------------------
// Row softmax in place on bf16 [rows][C=4096], one block per row, normalized.
// ---------------------------------------------------------------------------
__global__ __launch_bounds__(256) void softmax_row(unsigned short* __restrict__ E, int C)
{
  const long row = blockIdx.x;
  unsigned short* p = E + row * (long)C;
  const int tid = threadIdx.x;
  u16x8 u0 = *(const u16x8*)(p + tid * 16);
  u16x8 u1 = *(const u16x8*)(p + tid * 16 + 8);
  float v[16];
#pragma unroll
  for (int e = 0; e < 8; ++e) { v[e] = bf2f(u0[e]); v[8 + e] = bf2f(u1[e]); }
  float m = v[0];
#pragma unroll
  for (int e = 1; e < 16; ++e) m = fmaxf(m, v[e]);
#pragma unroll
  for (int o = 32; o >= 1; o >>= 1) m = fmaxf(m, __shfl_xor(m, o, 64));
  __shared__ float sm[4], ss[4];
  const int wv = tid >> 6, ln = tid & 63;
  if (ln == 0) sm[wv] = m;
  __syncthreads();
  m = fmaxf(fmaxf(sm[0], sm[1]), fmaxf(sm[2], sm[3]));
  float ev[16];
  float s = 0.f;
#pragma unroll
  for (int e = 0; e < 16; ++e) { ev[e] = __expf(v[e] - m); s += ev[e]; }
#pragma unroll
  for (int o = 32; o >= 1; o >>= 1) s += __shfl_xor(s, o, 64);
  if (ln == 0) ss[wv] = s;
  __syncthreads();
  s = ss[0] + ss[1] + ss[2] + ss[3];
  const float rs = 1.0f / s;
  u16x8 o0, o1;
#pragma unroll
  for (int e = 0; e < 8; ++e) { o0[e] = f2bf(ev[e] * rs); o1[e] = f2bf(ev[8 + e] * rs); }
  *(u16x8*)(p + tid * 16) = o0;
  *(u16x8*)(p + tid * 16 + 8) = o1;
}

// ---------------------------------------------------------------------------
// Transposes (64x64 LDS tiles) + weight convert (3 tensors in one dispatch)
// ---------------------------------------------------------------------------
__global__ __launch_bounds__(256) void tr_f32_bf16(
    const float* __restrict__ src, unsigned short* __restrict__ dst, int R, int C)
{
  __shared__ float t[64][65];
  const int c0 = blockIdx.x * 64, r0 = blockIdx.y * 64;
  const long bo = (long)blockIdx.z * R * C;
  const int tc = (threadIdx.x & 15) * 4;
  const int tr = threadIdx.x >> 4;
#pragma unroll
  for (int i = 0; i < 4; ++i) {
    const int r = tr + i * 16;
    float4 v = *(const float4*)&src[bo + (long)(r0 + r) * C + c0 + tc];
    t[r][tc] = v.x; t[r][tc + 1] = v.y; t[r][tc + 2] = v.z; t[r][tc + 3] = v.w;
  }
  __syncthreads();
#pragma unroll
  for (int i = 0; i < 4; ++i) {
    const int c = tr + i * 16;
    u16x4 o;
#pragma unroll
    for (int k = 0; k < 4; ++k) o[k] = f2bf(t[tc + k][c]);
    *(u16x4*)&dst[bo + (long)(c0 + c) * R + r0 + tc] = o;
  }
}

__global__ __launch_bounds__(256) void tr_bf16(
    const unsigned short* __restrict__ src, unsigned short* __restrict__ dst, int R, int C)
{
  __shared__ unsigned short t[64][68];
  const int c0 = blockIdx.x * 64, r0 = blockIdx.y * 64;
  const long bo = (long)blockIdx.z * R * C;
  const int tc = (threadIdx.x & 15) * 4;
  const int tr = threadIdx.x >> 4;
#pragma unroll
  for (int i = 0; i < 4; ++i) {
    const int r = tr + i * 16;
    u16x4 v = *(const u16x4*)&src[bo + (long)(r0 + r) * C + c0 + tc];
    t[r][tc] = v[0]; t[r][tc + 1] = v[1]; t[r][tc + 2] = v[2]; t[r][tc + 3] = v[3];
  }
  __syncthreads();
#pragma unroll
  for (int i = 0; i < 4; ++i) {
    const int c = tr + i * 16;
    u16x4 o;
#pragma unroll
    for (int k = 0; k < 4; ++k) o[k] = t[tc + k][c];
    *(u16x4*)&dst[bo + (long)(c0 + c) * R + r0 + tc] = o;
  }
}

__global__ __launch_bounds__(256) void cvt3(
    const float* __restrict__ s0, unsigned short* __restrict__ d0, long n0,
    const float* __restrict__ s1, unsigned short* __restrict__ d1, long n1,
    const float* __restrict__ s2, unsigned short* __restrict__ d2, long n2)
{
  long i = ((long)blockIdx.x * 256 + threadIdx.x) * 4;
  const float* s; unsigned short* d; long off;
  if (i < n0) { s = s0; d = d0; off = i; }
  else if (i < n0 + n1) { s = s1; d = d1; off = i - n0; }
  else if (i < n0 + n1 + n2) { s = s2; d = d2; off = i - n0 - n1; }
  else return;
  float4 v = *(const float4*)(s + off);
  u16x4 o;
  o[0] = f2bf(v.x); o[1] = f2bf(v.y); o[2] = f2bf(v.z); o[3] = f2bf(v.w);
  *(u16x4*)(d + off) = o;
}

// ---------------------------------------------------------------------------
extern "C" void kernel_launch(void* const* d_in, const int* in_sizes, int n_in,
                              void* d_out, int out_size, void* d_ws, size_t ws_size,
                              hipStream_t stream)
{
  const int NB = 2, CIN = 2048, HW = 4096, RC = 512, CT = 4096;
  const float* x = (const float*)d_in[0];

  char* wsb = (char*)d_ws;
  unsigned short* xT      = (unsigned short*)wsb;                 // [NB][HW][CIN]  32MB
  unsigned short* redT    = (unsigned short*)(wsb + 33554432);    // [NB][HW][RC]    8MB
  unsigned short* red     = (unsigned short*)(wsb + 41943040);    // [NB][RC][HW]    8MB
  unsigned short* a1T     = (unsigned short*)(wsb + 50331648);    // [NB][HW][RC]    8MB
  unsigned short* logitsT = (unsigned short*)(wsb + 58720256);    // [NB][HW][CT]   64MB
  unsigned short* wredb   = (unsigned short*)(wsb + 125829120);   // [RC][CIN]       2MB
  unsigned short* w1b     = (unsigned short*)(wsb + 127926272);   // [RC][RC]      0.5MB
  unsigned short* w2b     = (unsigned short*)(wsb + 128450560);   // [CT][RC]        4MB

  // x [NB][CIN][HW] f32 -> xT [NB][HW][CIN] bf16 (once)
  tr_f32_bf16<<<dim3(HW / 64, CIN / 64, NB), 256, 0, stream>>>(x, xT, CIN, HW);

  const long nw0 = (long)RC * CIN, nw1 = (long)RC * RC, nw2 = (long)CT * RC;
  const int cvtBlocks = (int)((nw0 + nw1 + nw2) / 4 / 256);

  for (int br = 0; br < 2; ++br) {
    const float* w_red = (const float*)d_in[1 + br * 5 + 0];
    const float* bn1f  = (const float*)d_in[1 + br * 5 + 1];
    const float* w1f   = (const float*)d_in[1 + br * 5 + 2];
    const float* bn2f  = (const float*)d_in[1 + br * 5 + 3];
    const float* w2f   = (const float*)d_in[1 + br * 5 + 4];

    cvt3<<<dim3(cvtBlocks), 256, 0, stream>>>(
        w_red, wredb, nw0, w1f, w1b, nw1, w2f, w2b, nw2);

    // G1: redT[t][r] = relu(bn1(sum_k xT[t][k] * Wred[r][k]))   M=HW,N=RC,K=CIN
    gemm8w<128, 1><<<dim3(RC / 128, HW / 128, NB), 512, 0, stream>>>(
        xT, (long)HW * CIN, wredb, 0, redT, (long)HW * RC, RC, HW, RC, CIN, bn1f);

    // red = transpose(redT)  -> [NB][RC][HW] (bmm A-operand)
    tr_bf16<<<dim3(RC / 64, HW / 64, NB), 256, 0, stream>>>(redT, red, HW, RC);

    // G2: a1T[t][r] = relu(bn2(sum_k redT[t][k] * W1[r][k]))    M=HW,N=RC,K=RC
    gemm8w<128, 1><<<dim3(RC / 128, HW / 128, NB), 512, 0, stream>>>(
        redT, (long)HW * RC, w1b, 0, a1T, (long)HW * RC, RC, HW, RC, RC, bn2f);

    // G3: logitsT[t][c] = sum_k a1T[t][k] * W2[c][k]            M=HW,N=CT,K=RC
    gemm8w<256, 0><<<dim3(CT / 128, HW / 256, NB), 512, 0, stream>>>(
        a1T, (long)HW * RC, w2b, 0, logitsT, (long)HW * CT, CT, HW, CT, RC, nullptr);

    // row softmax over c, normalized, in place -> E^T (the bmm B-operand)
    softmax_row<<<dim3(NB * HW), 256, 0, stream>>>(logitsT, CT);

    // G4: out[n][br*RC+r][t] = sum_k red[r][k] * ET[t][k]       M=RC,N=HW,K=CT
    gemm8w<128, 2><<<dim3(HW / 128, RC / 128, NB), 512, 0, stream>>>(
        red, (long)RC * HW, logitsT, (long)HW * CT,
        (float*)d_out + (long)br * RC * HW, (long)2 * RC * HW, HW,
        RC, HW, CT, nullptr);
  }
}